// Round 5
// baseline (449.958 us; speedup 1.0000x reference)
//
#include <hip/hip_runtime.h>
#include <math.h>

#define T_STEPS 730
#define NBASIN  16384
#define OUT_STRIDE (NBASIN * 4)

// ================= portability-guarded fast primitives =================
__device__ __forceinline__ float fexp2(float x) {   // 2^x
#if __has_builtin(__builtin_amdgcn_exp2f)
  return __builtin_amdgcn_exp2f(x);
#else
  return exp2f(x);
#endif
}
__device__ __forceinline__ float flog2(float x) {   // log2(x)
#if __has_builtin(__builtin_amdgcn_logf)
  return __builtin_amdgcn_logf(x);
#else
  return log2f(x);
#endif
}
__device__ __forceinline__ float frcp(float x) {    // 1/x (~1 ulp)
#if __has_builtin(__builtin_amdgcn_rcpf)
  return __builtin_amdgcn_rcpf(x);
#else
  return 1.0f / x;
#endif
}
__device__ __forceinline__ float clampf(float x, float lo, float hi) {
#if __has_builtin(__builtin_amdgcn_fmed3f)
  return __builtin_amdgcn_fmed3f(x, lo, hi);        // 1-instr clamp (finite inputs)
#else
  return fminf(fmaxf(x, lo), hi);
#endif
}
// fast pow for x in [0,1], y > 0: exp2(y*log2(x)); log2(0)=-inf -> exp2(-inf)=0 (correct limit)
__device__ __forceinline__ float fast_pow(float x, float y) {
  return fexp2(y * flog2(x));
}
// ---- DPP quad_perm helpers (VALU-speed cross-lane within a quad) ----
__device__ __forceinline__ float dpp_xor1(float v) {
#if __has_builtin(__builtin_amdgcn_mov_dpp)
  return __int_as_float(__builtin_amdgcn_mov_dpp(__float_as_int(v), 0xB1, 0xF, 0xF, true)); // [1,0,3,2]
#else
  return __shfl_xor(v, 1, 4);
#endif
}
__device__ __forceinline__ float dpp_xor2(float v) {
#if __has_builtin(__builtin_amdgcn_mov_dpp)
  return __int_as_float(__builtin_amdgcn_mov_dpp(__float_as_int(v), 0x4E, 0xF, 0xF, true)); // [2,3,0,1]
#else
  return __shfl_xor(v, 2, 4);
#endif
}

// 65536 threads = 1024 waves = exactly 1 wave/SIMD device-wide (intentional:
// sequential scan over T, parallel only in B; 4 lanes/basin maximizes
// resident-wave work while filling every SIMD).
//
// __launch_bounds__(256, 1): round-4 profile showed VGPR_Count=52 — the
// allocator targeted ~9 waves/EU (useless here: only 1024 waves exist
// device-wide) and evicted the ~90 loop-invariant weight/param registers,
// adding ~100 shuffle/reload instrs per step. min-waves-per-EU=1 unlocks
// the full register budget so the weight slices stay VGPR-resident.
__global__ __launch_bounds__(256, 1) void sac4dpl_kernel(
    const float2* __restrict__ pe_in,  // [T][B] (prcp, pet)
    const float*  __restrict__ kc_,
    const float*  __restrict__ um_,
    const float*  __restrict__ lm_,
    const float*  __restrict__ dm_,
    const float*  __restrict__ b_,
    const float*  __restrict__ im_,
    const float*  __restrict__ c_,
    const float*  __restrict__ w0_,
    const float*  __restrict__ W1,     // [8][16]
    const float*  __restrict__ b1,     // [16]
    const float*  __restrict__ W2,     // [16][8]
    const float*  __restrict__ b2,     // [8]
    const float*  __restrict__ W3,     // [8]
    const float*  __restrict__ b3,     // [1]
    float* __restrict__ out)           // [T][B][4] = (r, rim, e, pe)
{
  const int g   = blockIdx.x * blockDim.x + threadIdx.x; // 0..65535
  const int bas = g >> 2;   // basin id
  const int s   = g & 3;    // sub-lane within quad

  // ---- per-basin parameters ----
  const float kc = kc_[bas], um = um_[bas], lm = lm_[bas], dm = dm_[bas];
  const float bb = b_[bas],  im = im_[bas], cc = c_[bas];
  const float wm      = um + lm + dm;
  const float one_b   = 1.0f + bb;
  const float wmm     = wm * one_b;
  const float inv_b1  = 1.0f / one_b;    // once: precise div ok
  const float inv_wm  = 1.0f / wm;
  const float inv_wmm = 1.0f / wmm;
  const float wm_eps  = wm - 1e-5f;

  // ---- per-lane weight slices, VGPR-resident (no LDS, no reload in loop) ----
  // layer 1: lane owns neurons j = 4s+jj; static feats (kc,um,lm,dm,c) folded into s1.
  float s1[4], w1a[4], w1b[4], w1c[4];
  // layer 2 reduce-scatter: slot m holds coeffs for OWNER lane o = s^m (outputs 2o, 2o+1).
  float w2s[4][2][4];   // [slot m][u][jj]
#pragma unroll
  for (int jj = 0; jj < 4; ++jj) {
    const int j = 4 * s + jj;
    float acc = b1[j];
    acc = fmaf(kc, W1[0 * 16 + j], acc);
    acc = fmaf(um, W1[1 * 16 + j], acc);
    acc = fmaf(lm, W1[2 * 16 + j], acc);
    acc = fmaf(dm, W1[3 * 16 + j], acc);
    acc = fmaf(cc, W1[4 * 16 + j], acc);
    s1[jj]  = acc;
    w1a[jj] = W1[5 * 16 + j];   // * w0c
    w1b[jj] = W1[6 * 16 + j];   // * prcp
    w1c[jj] = W1[7 * 16 + j];   // * pet
#pragma unroll
    for (int m = 0; m < 4; ++m) {
      const int o = s ^ m;
#pragma unroll
      for (int u = 0; u < 2; ++u) w2s[m][u][jj] = W2[j * 8 + 2 * o + u];
    }
  }
  const float b2s0 = b2[2 * s], b2s1 = b2[2 * s + 1];   // bias folded once (slot 0 = owner s)
  // layer-3 weights pre-scaled by -log2(e): sigmoid(z) = rcp(1 + exp2(-log2e * z)),
  // and the scale is linear through the DPP butterfly -> fold it into W3/b3 at init.
  const float NL2E = -1.4426950408889634f;
  const float w3s0 = W3[2 * s] * NL2E, w3s1 = W3[2 * s + 1] * NL2E;
  const float b3r  = b3[0] * NL2E;

  // loop-invariant lane-role predicates (hoisted so the loop has pure cndmasks)
  const bool is0 = (s == 0), is1 = (s == 1), is2 = (s == 2);

  float w = w0_[bas];                 // running soil-moisture state
  unsigned oidx = (unsigned)g;        // 32-bit element index (out has <4G elements)

  auto step = [&](float2 cur) {
    const float prcp = fmaxf(cur.x, 0.0f);
    const float pet  = fmaxf(cur.y, 0.0f);
    const float w0c  = clampf(w, 0.0f, wm_eps);

    // layer 1: 4 owned neurons. w0c enters LAST so the prcp/pet partial sums
    // are independent of the serial w-chain (issueable during prior-step tail).
    float h1[4];
#pragma unroll
    for (int jj = 0; jj < 4; ++jj) {
      float z = s1[jj];
      z = fmaf(prcp, w1b[jj], z);
      z = fmaf(pet,  w1c[jj], z);
      z = fmaf(w0c,  w1a[jj], z);
      h1[jj] = fmaxf(z, 0.0f);
    }
    // layer 2 partials: slot m -> owner s^m (8 independent 4-FMA chains, high ILP)
    float p[4][2];
#pragma unroll
    for (int m = 0; m < 4; ++m) {
#pragma unroll
      for (int u = 0; u < 2; ++u) {
        float acc = (m == 0) ? (u == 0 ? b2s0 : b2s1) : 0.0f;
        acc = fmaf(h1[0], w2s[m][u][0], acc);
        acc = fmaf(h1[1], w2s[m][u][1], acc);
        acc = fmaf(h1[2], w2s[m][u][2], acc);
        acc = fmaf(h1[3], w2s[m][u][3], acc);
        p[m][u] = acc;
      }
    }
    // reduce-scatter stage A (xor2): partner lane s^2's slot m^2 targets my owner s^m
    const float q00 = p[0][0] + dpp_xor2(p[2][0]);
    const float q01 = p[0][1] + dpp_xor2(p[2][1]);
    const float q10 = p[1][0] + dpp_xor2(p[3][0]);
    const float q11 = p[1][1] + dpp_xor2(p[3][1]);
    // stage B (xor1): lane s ends with its own outputs 2s, 2s+1
    const float h2a = fmaxf(q00 + dpp_xor1(q10), 0.0f);
    const float h2b = fmaxf(q01 + dpp_xor1(q11), 0.0f);
    // layer 3 (weights pre-scaled by -log2e): per-lane partial then quad butterfly
    float z3p = fmaf(h2b, w3s1, h2a * w3s0);
    z3p += dpp_xor1(z3p);
    z3p += dpp_xor2(z3p);
    const float z3n = z3p + b3r;      // = -log2e * (h2.W3 + b3)

    // sigmoid * kc * pet: rcp(1 + exp2(z3n)) * kc * pet   (kc*pet is w-independent)
    const float eu = fexp2(z3n);      // exp(-z3)
    const float e  = frcp(1.0f + eu) * (kc * pet);

    const float pd   = prcp - e;
    const float pen  = fmaxf(pd, 0.0f);
    const float frac = clampf(fmaf(-w0c, inv_wm, 1.0f), 1e-5f, 1.0f);
    const float pw1  = fast_pow(frac, inv_b1);
    const float a    = fmaf(-wmm, pw1, wmm);             // wmm*(1 - pw1)
    const float r_full = pen - (wm - w0c);
    const float pa   = pen + a;
    const float resid = clampf(fmaf(-pa, inv_wmm, 1.0f), 0.0f, 1.0f);
    const float pw2  = fast_pow(resid, one_b);
    float r = (pa < wmm) ? fmaf(wm, pw2, r_full) : r_full;
    r = fmaxf(r, 0.0f);
    const float rim = pen * im;

    w = clampf(w0c + pd - r, 0.0f, wm_eps);

    const float val = is0 ? r : (is1 ? rim : (is2 ? e : pen));
    out[oidx] = val;                  // lane s writes comp s: wave = 256B contiguous
    oidx += OUT_STRIDE;
  };

  // ---- software-pipelined T loop: 4 named prefetch regs (no runtime-indexed
  // arrays -> no scratch), unroll x4, clamp-free indices via explicit epilogue ----
  unsigned ii = (unsigned)bas;        // 32-bit element index into pe_in
  float2 f0 = pe_in[ii + 0u * NBASIN];
  float2 f1 = pe_in[ii + 1u * NBASIN];
  float2 f2 = pe_in[ii + 2u * NBASIN];
  float2 f3 = pe_in[ii + 3u * NBASIN];
  ii += 4u * NBASIN;

  for (int t = 0; t <= T_STEPS - 8; t += 4) {   // t = 0,4,...,720 -> steps 0..723
    const float2 n0 = pe_in[ii + 0u * NBASIN];
    const float2 n1 = pe_in[ii + 1u * NBASIN];
    const float2 n2 = pe_in[ii + 2u * NBASIN];
    const float2 n3 = pe_in[ii + 3u * NBASIN];
    ii += 4u * NBASIN;
    step(f0); step(f1); step(f2); step(f3);
    f0 = n0; f1 = n1; f2 = n2; f3 = n3;
  }
  // epilogue: steps 724..727 from f0..f3, then 728, 729
  const float2 g0 = pe_in[ii + 0u * NBASIN];
  const float2 g1 = pe_in[ii + 1u * NBASIN];
  step(f0); step(f1); step(f2); step(f3);
  step(g0); step(g1);
}

extern "C" void kernel_launch(void* const* d_in, const int* in_sizes, int n_in,
                              void* d_out, int out_size, void* d_ws, size_t ws_size,
                              hipStream_t stream) {
  const float2* pe = (const float2*)d_in[0];
  const float* kc  = (const float*)d_in[1];
  const float* um  = (const float*)d_in[2];
  const float* lm  = (const float*)d_in[3];
  const float* dm  = (const float*)d_in[4];
  const float* bp  = (const float*)d_in[5];
  const float* im  = (const float*)d_in[6];
  const float* c   = (const float*)d_in[7];
  const float* w0  = (const float*)d_in[8];
  const float* W1  = (const float*)d_in[9];
  const float* b1  = (const float*)d_in[10];
  const float* W2  = (const float*)d_in[11];
  const float* b2  = (const float*)d_in[12];
  const float* W3  = (const float*)d_in[13];
  const float* b3  = (const float*)d_in[14];
  float* out = (float*)d_out;

  dim3 block(256);
  dim3 grid((NBASIN * 4) / 256);   // 256 blocks: 4 lanes/basin, 1 wave/SIMD device-wide
  hipLaunchKernelGGL(sac4dpl_kernel, grid, block, 0, stream,
                     pe, kc, um, lm, dm, bp, im, c, w0,
                     W1, b1, W2, b2, W3, b3, out);
}

// Round 7
// 447.810 us; speedup vs baseline: 1.0048x; 1.0048x over previous
//
#include <hip/hip_runtime.h>
#include <math.h>

#define T_STEPS 730
#define NBASIN  16384
#define OUT_STRIDE (NBASIN * 4)

// Pin a value into a VGPR: opaque asm def is NOT rematerializable, so the
// register allocator must keep it live instead of re-loading it from global
// memory every loop iteration (round-4/5 profiles: VGPR_Count=48..52 with
// ~51 loop-invariant weight floats -> compiler was reloading ~110 instr/step).
#define PIN(x) asm volatile("" : "+v"(x))

// ================= portability-guarded fast primitives =================
__device__ __forceinline__ float fexp2(float x) {   // 2^x
#if __has_builtin(__builtin_amdgcn_exp2f)
  return __builtin_amdgcn_exp2f(x);
#else
  return exp2f(x);
#endif
}
__device__ __forceinline__ float flog2(float x) {   // log2(x)
#if __has_builtin(__builtin_amdgcn_logf)
  return __builtin_amdgcn_logf(x);
#else
  return log2f(x);
#endif
}
__device__ __forceinline__ float frcp(float x) {    // 1/x (~1 ulp)
#if __has_builtin(__builtin_amdgcn_rcpf)
  return __builtin_amdgcn_rcpf(x);
#else
  return 1.0f / x;
#endif
}
__device__ __forceinline__ float clampf(float x, float lo, float hi) {
#if __has_builtin(__builtin_amdgcn_fmed3f)
  return __builtin_amdgcn_fmed3f(x, lo, hi);        // 1-instr clamp (finite inputs)
#else
  return fminf(fmaxf(x, lo), hi);
#endif
}
// fast pow for x in [0,1], y > 0: exp2(y*log2(x)); log2(0)=-inf -> exp2(-inf)=0 (correct limit)
__device__ __forceinline__ float fast_pow(float x, float y) {
  return fexp2(y * flog2(x));
}
// ---- DPP quad_perm helpers (VALU-speed cross-lane within a quad) ----
__device__ __forceinline__ float dpp_xor1(float v) {
#if __has_builtin(__builtin_amdgcn_mov_dpp)
  return __int_as_float(__builtin_amdgcn_mov_dpp(__float_as_int(v), 0xB1, 0xF, 0xF, true)); // [1,0,3,2]
#else
  return __shfl_xor(v, 1, 4);
#endif
}
__device__ __forceinline__ float dpp_xor2(float v) {
#if __has_builtin(__builtin_amdgcn_mov_dpp)
  return __int_as_float(__builtin_amdgcn_mov_dpp(__float_as_int(v), 0x4E, 0xF, 0xF, true)); // [2,3,0,1]
#else
  return __shfl_xor(v, 2, 4);
#endif
}

// 65536 threads = 1024 waves = exactly 1 wave/SIMD device-wide (intentional:
// sequential scan over T, parallel only in B; 4 lanes/basin maximizes
// resident-wave work while filling every SIMD).
__global__ __launch_bounds__(256, 1) void sac4dpl_kernel(
    const float2* __restrict__ pe_in,  // [T][B] (prcp, pet)
    const float*  __restrict__ kc_,
    const float*  __restrict__ um_,
    const float*  __restrict__ lm_,
    const float*  __restrict__ dm_,
    const float*  __restrict__ b_,
    const float*  __restrict__ im_,
    const float*  __restrict__ c_,
    const float*  __restrict__ w0_,
    const float*  __restrict__ W1,     // [8][16]
    const float*  __restrict__ b1,     // [16]
    const float*  __restrict__ W2,     // [16][8]
    const float*  __restrict__ b2,     // [8]
    const float*  __restrict__ W3,     // [8]
    const float*  __restrict__ b3,     // [1]
    float* __restrict__ out)           // [T][B][4] = (r, rim, e, pe)
{
  const int g   = blockIdx.x * blockDim.x + threadIdx.x; // 0..65535
  const int bas = g >> 2;   // basin id
  const int s   = g & 3;    // sub-lane within quad

  // ---- per-basin parameters ----
  const float kc = kc_[bas], um = um_[bas], lm = lm_[bas], dm = dm_[bas];
  const float bb = b_[bas];
  float im = im_[bas];
  const float cc = c_[bas];
  float wm      = um + lm + dm;
  float one_b   = 1.0f + bb;
  float wmm     = wm * one_b;
  float inv_b1  = 1.0f / one_b;    // once: precise div ok
  float inv_wm  = 1.0f / wm;
  float inv_wmm = 1.0f / wmm;
  float wm_eps  = wm - 1e-5f;
  float kcp     = kc;              // kept live for e = sigmoid*kc*pet

  // ---- per-lane weight slices ----
  // layer 1: lane owns neurons j = 4s+jj; static feats (kc,um,lm,dm,c) folded into s1.
  float s1[4], w1a[4], w1b[4], w1c[4];
  // layer 2 reduce-scatter: slot m holds coeffs for OWNER lane o = s^m (outputs 2o, 2o+1).
  float w2s[4][2][4];   // [slot m][u][jj]
#pragma unroll
  for (int jj = 0; jj < 4; ++jj) {
    const int j = 4 * s + jj;
    float acc = b1[j];
    acc = fmaf(kc, W1[0 * 16 + j], acc);
    acc = fmaf(um, W1[1 * 16 + j], acc);
    acc = fmaf(lm, W1[2 * 16 + j], acc);
    acc = fmaf(dm, W1[3 * 16 + j], acc);
    acc = fmaf(cc, W1[4 * 16 + j], acc);
    s1[jj]  = acc;
    w1a[jj] = W1[5 * 16 + j];   // * w0c
    w1b[jj] = W1[6 * 16 + j];   // * prcp
    w1c[jj] = W1[7 * 16 + j];   // * pet
#pragma unroll
    for (int m = 0; m < 4; ++m) {
      const int o = s ^ m;
#pragma unroll
      for (int u = 0; u < 2; ++u) w2s[m][u][jj] = W2[j * 8 + 2 * o + u];
    }
  }
  float b2s0 = b2[2 * s], b2s1 = b2[2 * s + 1];   // bias folded once (slot 0 = owner s)
  // layer-3 weights pre-scaled by -log2(e): sigmoid(z) = rcp(1 + exp2(-log2e * z)).
  const float NL2E = -1.4426950408889634f;
  float w3s0 = W3[2 * s] * NL2E, w3s1 = W3[2 * s + 1] * NL2E;
  float b3r  = b3[0] * NL2E;

  // ---- PIN all loop-invariants into VGPRs (defeat load-rematerialization) ----
#pragma unroll
  for (int jj = 0; jj < 4; ++jj) {
    PIN(s1[jj]); PIN(w1a[jj]); PIN(w1b[jj]); PIN(w1c[jj]);
#pragma unroll
    for (int m = 0; m < 4; ++m) { PIN(w2s[m][0][jj]); PIN(w2s[m][1][jj]); }
  }
  PIN(b2s0); PIN(b2s1); PIN(w3s0); PIN(w3s1); PIN(b3r);
  PIN(im); PIN(kcp);
  PIN(wm); PIN(one_b); PIN(wmm); PIN(inv_b1); PIN(inv_wm); PIN(inv_wmm); PIN(wm_eps);

  // loop-invariant lane-role predicates
  const bool is0 = (s == 0), is1 = (s == 1), is2 = (s == 2);

  float w = w0_[bas];                 // running soil-moisture state
  unsigned oidx = (unsigned)g;        // 32-bit element index (out has <4G elements)

  auto step = [&](float2 cur) {
    const float prcp = fmaxf(cur.x, 0.0f);
    const float pet  = fmaxf(cur.y, 0.0f);
    const float w0c  = clampf(w, 0.0f, wm_eps);

    // layer 1: 4 owned neurons. w0c enters LAST so the prcp/pet partial sums
    // are independent of the serial w-chain (issueable during prior-step tail).
    float h1[4];
#pragma unroll
    for (int jj = 0; jj < 4; ++jj) {
      float z = s1[jj];
      z = fmaf(prcp, w1b[jj], z);
      z = fmaf(pet,  w1c[jj], z);
      z = fmaf(w0c,  w1a[jj], z);
      h1[jj] = fmaxf(z, 0.0f);
    }
    // layer 2 partials: slot m -> owner s^m (8 independent 4-FMA chains, high ILP)
    float p[4][2];
#pragma unroll
    for (int m = 0; m < 4; ++m) {
#pragma unroll
      for (int u = 0; u < 2; ++u) {
        float acc = (m == 0) ? (u == 0 ? b2s0 : b2s1) : 0.0f;
        acc = fmaf(h1[0], w2s[m][u][0], acc);
        acc = fmaf(h1[1], w2s[m][u][1], acc);
        acc = fmaf(h1[2], w2s[m][u][2], acc);
        acc = fmaf(h1[3], w2s[m][u][3], acc);
        p[m][u] = acc;
      }
    }
    // reduce-scatter stage A (xor2): partner lane s^2's slot m^2 targets my owner s^m
    const float q00 = p[0][0] + dpp_xor2(p[2][0]);
    const float q01 = p[0][1] + dpp_xor2(p[2][1]);
    const float q10 = p[1][0] + dpp_xor2(p[3][0]);
    const float q11 = p[1][1] + dpp_xor2(p[3][1]);
    // stage B (xor1): lane s ends with its own outputs 2s, 2s+1
    const float h2a = fmaxf(q00 + dpp_xor1(q10), 0.0f);
    const float h2b = fmaxf(q01 + dpp_xor1(q11), 0.0f);
    // layer 3 (weights pre-scaled by -log2e): per-lane partial then quad butterfly
    float z3p = fmaf(h2b, w3s1, h2a * w3s0);
    z3p += dpp_xor1(z3p);
    z3p += dpp_xor2(z3p);
    const float z3n = z3p + b3r;      // = -log2e * (h2.W3 + b3)

    // sigmoid * kc * pet: rcp(1 + exp2(z3n)) * kc * pet
    const float eu = fexp2(z3n);      // exp(-z3)
    const float e  = frcp(1.0f + eu) * (kcp * pet);

    const float pd   = prcp - e;
    const float pen  = fmaxf(pd, 0.0f);
    const float frac = clampf(fmaf(-w0c, inv_wm, 1.0f), 1e-5f, 1.0f);
    const float pw1  = fast_pow(frac, inv_b1);
    const float a    = fmaf(-wmm, pw1, wmm);             // wmm*(1 - pw1)
    const float r_full = pen - (wm - w0c);
    const float pa   = pen + a;
    const float resid = clampf(fmaf(-pa, inv_wmm, 1.0f), 0.0f, 1.0f);
    const float pw2  = fast_pow(resid, one_b);
    float r = (pa < wmm) ? fmaf(wm, pw2, r_full) : r_full;
    r = fmaxf(r, 0.0f);
    const float rim = pen * im;

    w = clampf(w0c + pd - r, 0.0f, wm_eps);

    const float val = is0 ? r : (is1 ? rim : (is2 ? e : pen));
    out[oidx] = val;                  // lane s writes comp s: wave = 256B contiguous
    oidx += OUT_STRIDE;
  };

  // ---- software-pipelined T loop: 4 named prefetch regs (no runtime-indexed
  // arrays -> no scratch), unroll x4, clamp-free indices via explicit epilogue ----
  unsigned ii = (unsigned)bas;        // 32-bit element index into pe_in
  float2 f0 = pe_in[ii + 0u * NBASIN];
  float2 f1 = pe_in[ii + 1u * NBASIN];
  float2 f2 = pe_in[ii + 2u * NBASIN];
  float2 f3 = pe_in[ii + 3u * NBASIN];
  ii += 4u * NBASIN;

  for (int t = 0; t <= T_STEPS - 8; t += 4) {   // t = 0,4,...,720 -> steps 0..723
    const float2 n0 = pe_in[ii + 0u * NBASIN];
    const float2 n1 = pe_in[ii + 1u * NBASIN];
    const float2 n2 = pe_in[ii + 2u * NBASIN];
    const float2 n3 = pe_in[ii + 3u * NBASIN];
    ii += 4u * NBASIN;
    step(f0); step(f1); step(f2); step(f3);
    f0 = n0; f1 = n1; f2 = n2; f3 = n3;
  }
  // epilogue: steps 724..727 from f0..f3, then 728, 729
  const float2 g0 = pe_in[ii + 0u * NBASIN];
  const float2 g1 = pe_in[ii + 1u * NBASIN];
  step(f0); step(f1); step(f2); step(f3);
  step(g0); step(g1);
}

extern "C" void kernel_launch(void* const* d_in, const int* in_sizes, int n_in,
                              void* d_out, int out_size, void* d_ws, size_t ws_size,
                              hipStream_t stream) {
  const float2* pe = (const float2*)d_in[0];
  const float* kc  = (const float*)d_in[1];
  const float* um  = (const float*)d_in[2];
  const float* lm  = (const float*)d_in[3];
  const float* dm  = (const float*)d_in[4];
  const float* bp  = (const float*)d_in[5];
  const float* im  = (const float*)d_in[6];
  const float* c   = (const float*)d_in[7];
  const float* w0  = (const float*)d_in[8];
  const float* W1  = (const float*)d_in[9];
  const float* b1  = (const float*)d_in[10];
  const float* W2  = (const float*)d_in[11];
  const float* b2  = (const float*)d_in[12];
  const float* W3  = (const float*)d_in[13];
  const float* b3  = (const float*)d_in[14];
  float* out = (float*)d_out;

  dim3 block(256);
  dim3 grid((NBASIN * 4) / 256);   // 256 blocks: 4 lanes/basin, 1 wave/SIMD device-wide
  hipLaunchKernelGGL(sac4dpl_kernel, grid, block, 0, stream,
                     pe, kc, um, lm, dm, bp, im, c, w0,
                     W1, b1, W2, b2, W3, b3, out);
}

// Round 8
// 397.283 us; speedup vs baseline: 1.1326x; 1.1272x over previous
//
#include <hip/hip_runtime.h>
#include <math.h>

#define T_STEPS 730
#define NBASIN  16384
#define OUT_STRIDE (NBASIN * 4)

// Pin a value into a VGPR: opaque asm def is NOT rematerializable.
// R7 showed PIN alone is insufficient (allocator spills pinned values to the
// AGPR file instead: VGPR_Count stayed 48, ~110 extra VALU instr/step of
// v_accvgpr traffic). Combined with amdgpu_waves_per_eu(1,1) below, the
// allocator has no occupancy incentive to spill and must use plain VGPRs.
#define PIN(x) asm volatile("" : "+v"(x))

// ================= portability-guarded fast primitives =================
__device__ __forceinline__ float fexp2(float x) {   // 2^x
#if __has_builtin(__builtin_amdgcn_exp2f)
  return __builtin_amdgcn_exp2f(x);
#else
  return exp2f(x);
#endif
}
__device__ __forceinline__ float flog2(float x) {   // log2(x)
#if __has_builtin(__builtin_amdgcn_logf)
  return __builtin_amdgcn_logf(x);
#else
  return log2f(x);
#endif
}
__device__ __forceinline__ float frcp(float x) {    // 1/x (~1 ulp)
#if __has_builtin(__builtin_amdgcn_rcpf)
  return __builtin_amdgcn_rcpf(x);
#else
  return 1.0f / x;
#endif
}
__device__ __forceinline__ float clampf(float x, float lo, float hi) {
#if __has_builtin(__builtin_amdgcn_fmed3f)
  return __builtin_amdgcn_fmed3f(x, lo, hi);        // 1-instr clamp (finite inputs)
#else
  return fminf(fmaxf(x, lo), hi);
#endif
}
// fast pow for x in [0,1], y > 0: exp2(y*log2(x)); log2(0)=-inf -> exp2(-inf)=0 (correct limit)
__device__ __forceinline__ float fast_pow(float x, float y) {
  return fexp2(y * flog2(x));
}
// ---- DPP quad_perm helpers (VALU-speed cross-lane within a quad) ----
__device__ __forceinline__ float dpp_xor1(float v) {
#if __has_builtin(__builtin_amdgcn_mov_dpp)
  return __int_as_float(__builtin_amdgcn_mov_dpp(__float_as_int(v), 0xB1, 0xF, 0xF, true)); // [1,0,3,2]
#else
  return __shfl_xor(v, 1, 4);
#endif
}
__device__ __forceinline__ float dpp_xor2(float v) {
#if __has_builtin(__builtin_amdgcn_mov_dpp)
  return __int_as_float(__builtin_amdgcn_mov_dpp(__float_as_int(v), 0x4E, 0xF, 0xF, true)); // [2,3,0,1]
#else
  return __shfl_xor(v, 2, 4);
#endif
}

// 65536 threads = 1024 waves = exactly 1 wave/SIMD device-wide (intentional:
// sequential scan over T, parallel only in B; 4 lanes/basin maximizes
// resident-wave work while filling every SIMD).
//
// amdgpu_waves_per_eu(1,1): R5/R7 showed the allocator targets its default
// ~10 waves/EU occupancy (<=48 VGPR) regardless of __launch_bounds__'s
// min-waves FLOOR, spilling ~90 loop-invariant floats to AGPRs at ~110
// VALU instr/step of v_accvgpr traffic. min=max=1 removes the incentive:
// only 1024 waves exist device-wide, so occupancy >1 wave/EU is worthless.
__attribute__((amdgpu_flat_work_group_size(256, 256), amdgpu_waves_per_eu(1, 1)))
__global__ void sac4dpl_kernel(
    const float2* __restrict__ pe_in,  // [T][B] (prcp, pet)
    const float*  __restrict__ kc_,
    const float*  __restrict__ um_,
    const float*  __restrict__ lm_,
    const float*  __restrict__ dm_,
    const float*  __restrict__ b_,
    const float*  __restrict__ im_,
    const float*  __restrict__ c_,
    const float*  __restrict__ w0_,
    const float*  __restrict__ W1,     // [8][16]
    const float*  __restrict__ b1,     // [16]
    const float*  __restrict__ W2,     // [16][8]
    const float*  __restrict__ b2,     // [8]
    const float*  __restrict__ W3,     // [8]
    const float*  __restrict__ b3,     // [1]
    float* __restrict__ out)           // [T][B][4] = (r, rim, e, pe)
{
  const int g   = blockIdx.x * blockDim.x + threadIdx.x; // 0..65535
  const int bas = g >> 2;   // basin id
  const int s   = g & 3;    // sub-lane within quad

  // ---- per-basin parameters ----
  const float kc = kc_[bas], um = um_[bas], lm = lm_[bas], dm = dm_[bas];
  const float bb = b_[bas];
  float im = im_[bas];
  const float cc = c_[bas];
  float wm      = um + lm + dm;
  float one_b   = 1.0f + bb;
  float wmm     = wm * one_b;
  float inv_b1  = 1.0f / one_b;    // once: precise div ok
  float inv_wm  = 1.0f / wm;
  float inv_wmm = 1.0f / wmm;
  float wm_eps  = wm - 1e-5f;
  float kcp     = kc;              // kept live for e = sigmoid*kc*pet

  // ---- per-lane weight slices ----
  // layer 1: lane owns neurons j = 4s+jj; static feats (kc,um,lm,dm,c) folded into s1.
  float s1[4], w1a[4], w1b[4], w1c[4];
  // layer 2 reduce-scatter: slot m holds coeffs for OWNER lane o = s^m (outputs 2o, 2o+1).
  float w2s[4][2][4];   // [slot m][u][jj]
#pragma unroll
  for (int jj = 0; jj < 4; ++jj) {
    const int j = 4 * s + jj;
    float acc = b1[j];
    acc = fmaf(kc, W1[0 * 16 + j], acc);
    acc = fmaf(um, W1[1 * 16 + j], acc);
    acc = fmaf(lm, W1[2 * 16 + j], acc);
    acc = fmaf(dm, W1[3 * 16 + j], acc);
    acc = fmaf(cc, W1[4 * 16 + j], acc);
    s1[jj]  = acc;
    w1a[jj] = W1[5 * 16 + j];   // * w0c
    w1b[jj] = W1[6 * 16 + j];   // * prcp
    w1c[jj] = W1[7 * 16 + j];   // * pet
#pragma unroll
    for (int m = 0; m < 4; ++m) {
      const int o = s ^ m;
#pragma unroll
      for (int u = 0; u < 2; ++u) w2s[m][u][jj] = W2[j * 8 + 2 * o + u];
    }
  }
  float b2s0 = b2[2 * s], b2s1 = b2[2 * s + 1];   // bias folded once (slot 0 = owner s)
  // layer-3 weights pre-scaled by -log2(e): sigmoid(z) = rcp(1 + exp2(-log2e * z)).
  const float NL2E = -1.4426950408889634f;
  float w3s0 = W3[2 * s] * NL2E, w3s1 = W3[2 * s + 1] * NL2E;
  float b3r  = b3[0] * NL2E;

  // ---- PIN all loop-invariants into VGPRs (defeat load-rematerialization) ----
#pragma unroll
  for (int jj = 0; jj < 4; ++jj) {
    PIN(s1[jj]); PIN(w1a[jj]); PIN(w1b[jj]); PIN(w1c[jj]);
#pragma unroll
    for (int m = 0; m < 4; ++m) { PIN(w2s[m][0][jj]); PIN(w2s[m][1][jj]); }
  }
  PIN(b2s0); PIN(b2s1); PIN(w3s0); PIN(w3s1); PIN(b3r);
  PIN(im); PIN(kcp);
  PIN(wm); PIN(one_b); PIN(wmm); PIN(inv_b1); PIN(inv_wm); PIN(inv_wmm); PIN(wm_eps);

  // loop-invariant lane-role predicates
  const bool is0 = (s == 0), is1 = (s == 1), is2 = (s == 2);

  float w = w0_[bas];                 // running soil-moisture state
  unsigned oidx = (unsigned)g;        // 32-bit element index (out has <4G elements)

  auto step = [&](float2 cur) {
    const float prcp = fmaxf(cur.x, 0.0f);
    const float pet  = fmaxf(cur.y, 0.0f);
    const float w0c  = clampf(w, 0.0f, wm_eps);

    // layer 1: 4 owned neurons. w0c enters LAST so the prcp/pet partial sums
    // are independent of the serial w-chain (issueable during prior-step tail).
    float h1[4];
#pragma unroll
    for (int jj = 0; jj < 4; ++jj) {
      float z = s1[jj];
      z = fmaf(prcp, w1b[jj], z);
      z = fmaf(pet,  w1c[jj], z);
      z = fmaf(w0c,  w1a[jj], z);
      h1[jj] = fmaxf(z, 0.0f);
    }
    // layer 2 partials: slot m -> owner s^m (8 independent 4-FMA chains, high ILP)
    float p[4][2];
#pragma unroll
    for (int m = 0; m < 4; ++m) {
#pragma unroll
      for (int u = 0; u < 2; ++u) {
        float acc = (m == 0) ? (u == 0 ? b2s0 : b2s1) : 0.0f;
        acc = fmaf(h1[0], w2s[m][u][0], acc);
        acc = fmaf(h1[1], w2s[m][u][1], acc);
        acc = fmaf(h1[2], w2s[m][u][2], acc);
        acc = fmaf(h1[3], w2s[m][u][3], acc);
        p[m][u] = acc;
      }
    }
    // reduce-scatter stage A (xor2): partner lane s^2's slot m^2 targets my owner s^m
    const float q00 = p[0][0] + dpp_xor2(p[2][0]);
    const float q01 = p[0][1] + dpp_xor2(p[2][1]);
    const float q10 = p[1][0] + dpp_xor2(p[3][0]);
    const float q11 = p[1][1] + dpp_xor2(p[3][1]);
    // stage B (xor1): lane s ends with its own outputs 2s, 2s+1
    const float h2a = fmaxf(q00 + dpp_xor1(q10), 0.0f);
    const float h2b = fmaxf(q01 + dpp_xor1(q11), 0.0f);
    // layer 3 (weights pre-scaled by -log2e): per-lane partial then quad butterfly
    float z3p = fmaf(h2b, w3s1, h2a * w3s0);
    z3p += dpp_xor1(z3p);
    z3p += dpp_xor2(z3p);
    const float z3n = z3p + b3r;      // = -log2e * (h2.W3 + b3)

    // sigmoid * kc * pet: rcp(1 + exp2(z3n)) * kc * pet
    const float eu = fexp2(z3n);      // exp(-z3)
    const float e  = frcp(1.0f + eu) * (kcp * pet);

    const float pd   = prcp - e;
    const float pen  = fmaxf(pd, 0.0f);
    const float frac = clampf(fmaf(-w0c, inv_wm, 1.0f), 1e-5f, 1.0f);
    const float pw1  = fast_pow(frac, inv_b1);
    const float a    = fmaf(-wmm, pw1, wmm);             // wmm*(1 - pw1)
    const float r_full = pen - (wm - w0c);
    const float pa   = pen + a;
    const float resid = clampf(fmaf(-pa, inv_wmm, 1.0f), 0.0f, 1.0f);
    const float pw2  = fast_pow(resid, one_b);
    float r = (pa < wmm) ? fmaf(wm, pw2, r_full) : r_full;
    r = fmaxf(r, 0.0f);
    const float rim = pen * im;

    w = clampf(w0c + pd - r, 0.0f, wm_eps);

    const float val = is0 ? r : (is1 ? rim : (is2 ? e : pen));
    out[oidx] = val;                  // lane s writes comp s: wave = 256B contiguous
    oidx += OUT_STRIDE;
  };

  // ---- software-pipelined T loop: 4 named prefetch regs (no runtime-indexed
  // arrays -> no scratch), unroll x4, clamp-free indices via explicit epilogue ----
  unsigned ii = (unsigned)bas;        // 32-bit element index into pe_in
  float2 f0 = pe_in[ii + 0u * NBASIN];
  float2 f1 = pe_in[ii + 1u * NBASIN];
  float2 f2 = pe_in[ii + 2u * NBASIN];
  float2 f3 = pe_in[ii + 3u * NBASIN];
  ii += 4u * NBASIN;

  for (int t = 0; t <= T_STEPS - 8; t += 4) {   // t = 0,4,...,720 -> steps 0..723
    const float2 n0 = pe_in[ii + 0u * NBASIN];
    const float2 n1 = pe_in[ii + 1u * NBASIN];
    const float2 n2 = pe_in[ii + 2u * NBASIN];
    const float2 n3 = pe_in[ii + 3u * NBASIN];
    ii += 4u * NBASIN;
    step(f0); step(f1); step(f2); step(f3);
    f0 = n0; f1 = n1; f2 = n2; f3 = n3;
  }
  // epilogue: steps 724..727 from f0..f3, then 728, 729
  const float2 g0 = pe_in[ii + 0u * NBASIN];
  const float2 g1 = pe_in[ii + 1u * NBASIN];
  step(f0); step(f1); step(f2); step(f3);
  step(g0); step(g1);
}

extern "C" void kernel_launch(void* const* d_in, const int* in_sizes, int n_in,
                              void* d_out, int out_size, void* d_ws, size_t ws_size,
                              hipStream_t stream) {
  const float2* pe = (const float2*)d_in[0];
  const float* kc  = (const float*)d_in[1];
  const float* um  = (const float*)d_in[2];
  const float* lm  = (const float*)d_in[3];
  const float* dm  = (const float*)d_in[4];
  const float* bp  = (const float*)d_in[5];
  const float* im  = (const float*)d_in[6];
  const float* c   = (const float*)d_in[7];
  const float* w0  = (const float*)d_in[8];
  const float* W1  = (const float*)d_in[9];
  const float* b1  = (const float*)d_in[10];
  const float* W2  = (const float*)d_in[11];
  const float* b2  = (const float*)d_in[12];
  const float* W3  = (const float*)d_in[13];
  const float* b3  = (const float*)d_in[14];
  float* out = (float*)d_out;

  dim3 block(256);
  dim3 grid((NBASIN * 4) / 256);   // 256 blocks: 4 lanes/basin, 1 wave/SIMD device-wide
  hipLaunchKernelGGL(sac4dpl_kernel, grid, block, 0, stream,
                     pe, kc, um, lm, dm, bp, im, c, w0,
                     W1, b1, W2, b2, W3, b3, out);
}